// Round 11
// baseline (217.107 us; speedup 1.0000x reference)
//
#include <hip/hip_runtime.h>
#include <hip/hip_cooperative_groups.h>
#include <stdint.h>

#define L_DIM 1024
#define N_DIM 64
#define D_DIM 64
#define O_DIM 1024
#define ND    4096              // slice stride (floats) for x / upfold rows
#define NT    8                 // O tiles per team (fallback kernel)

typedef float    floatx16 __attribute__((ext_vector_type(16)));
typedef _Float16 half8    __attribute__((ext_vector_type(8)));
typedef _Float16 h2       __attribute__((ext_vector_type(2)));
typedef __fp16   fp16x2   __attribute__((ext_vector_type(2)));

// ---------- fragment-order U image (r9-verified layout) ----------
// per 64-o tile (16384 B):
//   G1 [team t][kk]          : 2x4 chunks of 1024 B at  t*4096 + kk*1024
//       lane p, 16B = Ub[t*32 + (p&31)][d = 16*kk + 8*(p>>5) .. +8]   (8 f16)
//   G2 [t][c2][r]  (base 8192): 2x2x2 chunks of 1024 B at 8192 + t*4096 + c2*2048 + r*1024
//       lane p, 16B = UtT[r*32 + (p&31)][op = t*16 + 8*c2 + 4*(p>>5) .. +4]  (4 u32 o-pairs)
#define IMG_BYTES 16384
#define WS_NEEDED ((size_t)N_DIM * 16 * IMG_BYTES)   // 16 MiB

#define BUF_STRIDE_FB 17920     // fallback kernel: Ub 9216 B + Ut2 8704 B

__device__ __forceinline__ uint32_t pkh2(float a, float b) {
    fp16x2 p = __builtin_amdgcn_cvt_pkrtz(a, b);   // v_cvt_pkrtz_f16_f32
    return __builtin_bit_cast(uint32_t, p);
}

__device__ __forceinline__ half8 mk_frag(uint32_t a, uint32_t b, uint32_t c, uint32_t d) {
    union { uint32_t u[4]; half8 v; } U;
    U.u[0] = a; U.u[1] = b; U.u[2] = c; U.u[3] = d;
    return U.v;
}

// sigmoid(s/8) - 0.5 = 0.5*tanh(s/16), odd poly in v=(s/16)^2, packed fp16.
__device__ __forceinline__ uint32_t psig(float s0, float s1) {
    const h2 HI = {(_Float16)41.6f,        (_Float16)41.6f};
    const h2 LO = {(_Float16)-41.6f,       (_Float16)-41.6f};
    const h2 SC = {(_Float16)0.0625f,      (_Float16)0.0625f};
    const h2 C0 = {(_Float16)0.03099238f,  (_Float16)0.03099238f};
    const h2 C1 = {(_Float16)-0.00842090f, (_Float16)-0.00842090f};
    const h2 C2 = {(_Float16)0.00151845f,  (_Float16)0.00151845f};
    const h2 C3 = {(_Float16)-1.02197e-4f, (_Float16)-1.02197e-4f};
    h2 s = __builtin_bit_cast(h2, pkh2(s0, s1));
    s = __builtin_elementwise_min(s, HI);
    s = __builtin_elementwise_max(s, LO);
    h2 ha = s * SC;
    h2 v  = ha * ha;
    h2 w  = C2 + v * C3;
    w     = C1 + v * w;
    w     = C0 + v * w;
    h2 f  = s * w;
    return __builtin_bit_cast(uint32_t, f);
}

// Coalesced U tile load: thread (r8, c) takes rows 2*r8+32j (va)/+1 (vb).
__device__ __forceinline__ void load_tile(const float* ubase, int ot,
                                          int r8, int c, float4* va, float4* vb) {
    const float* pr = ubase + (size_t)(ot * 64 + 2 * r8) * ND + 4 * c;
    #pragma unroll
    for (int j = 0; j < 2; ++j) {
        va[j] = *(const float4*)(pr + (size_t)(32 * j) * ND);
        vb[j] = *(const float4*)(pr + (size_t)(32 * j) * ND + ND);
    }
}

// ---- pack one tile's registers into the fragment-order image (r9-verified) ----
__device__ __forceinline__ void pack_frag_image(unsigned char* tb, int r8, int c,
                                                const float4* va, const float4* vb)
{
    // G1
    const int kk = c >> 2;
    const int hh = (c >> 1) & 1;
    const int co = (c & 1) * 8;
    #pragma unroll
    for (int j = 0; j < 2; ++j) {
        const int o0 = 2 * r8 + 32 * j;
        unsigned char* g1 = tb + j * 4096 + kk * 1024 + co;
        *(uint2*)(g1 + ((o0 & 31) + 32 * hh) * 16) =
            make_uint2(pkh2(va[j].x, va[j].y), pkh2(va[j].z, va[j].w));
        *(uint2*)(g1 + (((o0 + 1) & 31) + 32 * hh) * 16) =
            make_uint2(pkh2(vb[j].x, vb[j].y), pkh2(vb[j].z, vb[j].w));
    }
    // G2
    #pragma unroll
    for (int j = 0; j < 2; ++j) {
        const int op   = r8 + 16 * j;
        const int g    = op >> 2;
        const int slot = op & 3;
        const int t2   = g >> 2;
        const int c22  = (g >> 1) & 1;
        const int h2i  = g & 1;
        const float* pa = (const float*)&va[j];
        const float* pb = (const float*)&vb[j];
        #pragma unroll
        for (int col = 0; col < 4; ++col) {
            const int d    = 4 * c + col;
            const int r    = d >> 5;
            const int lane = (d & 31) + 32 * h2i;
            *(uint32_t*)(tb + 8192 + t2 * 4096 + c22 * 2048 + r * 1024
                         + lane * 16 + slot * 4) = pkh2(pa[col], pb[col]);
        }
    }
}

// ================= kernel A (fallback path): U -> fragment-order image =================
__global__ void __launch_bounds__(256)
conv_kernel(const float* __restrict__ up, unsigned char* __restrict__ img)
{
    const int tid = threadIdx.x;
    const int r8  = tid >> 4;
    const int c   = tid & 15;
    const int n   = blockIdx.x;
    const int ot  = blockIdx.y;

    const float* ubase = up + (size_t)n * D_DIM;
    float4 va[2], vb[2];
    load_tile(ubase, ot, r8, c, va, vb);
    pack_frag_image(img + (size_t)(n * 16 + ot) * IMG_BYTES, r8, c, va, vb);
}

// ---- per-tile fragment loads: 8 lane-contiguous dwordx4 ----
__device__ __forceinline__ void load_frags(const unsigned char* tb, int team, int lane,
                                           half8* Ak, half8* G2) {
    const unsigned char* g1 = tb + team * 4096 + (size_t)lane * 16;
    #pragma unroll
    for (int kk = 0; kk < 4; ++kk)
        Ak[kk] = *(const half8*)(g1 + kk * 1024);
    const unsigned char* g2 = tb + 8192 + team * 4096 + (size_t)lane * 16;
    #pragma unroll
    for (int i = 0; i < 4; ++i)
        G2[i] = *(const half8*)(g2 + i * 1024);   // [0]=A0c0 [1]=A1c0 [2]=A0c1 [3]=A1c1
}

// ---- per-tile compute: both l-halves share the U fragments ----
__device__ __forceinline__ void compute_tile(const half8* Ak, const half8* G2,
                                             const half8* Xf0, const half8* Xf1, int h,
                                             floatx16& F00, floatx16& F01,
                                             floatx16& F10, floatx16& F11)
{
    floatx16 S0, S1;
    #pragma unroll
    for (int i = 0; i < 16; ++i) { S0[i] = 0.0f; S1[i] = 0.0f; }
    #pragma unroll
    for (int kk = 0; kk < 4; ++kk) {
        S0 = __builtin_amdgcn_mfma_f32_32x32x16_f16(Ak[kk], Xf0[kk], S0, 0, 0, 0);
        S1 = __builtin_amdgcn_mfma_f32_32x32x16_f16(Ak[kk], Xf1[kk], S1, 0, 0, 0);
    }

    uint32_t P0[8], P1[8];
    #pragma unroll
    for (int m = 0; m < 8; ++m) { P0[m] = psig(S0[2*m], S0[2*m+1]);
                                  P1[m] = psig(S1[2*m], S1[2*m+1]); }

    uint32_t R0[4], R1[4];
    #pragma unroll
    for (int c2 = 0; c2 < 2; ++c2) {
        const int t4 = c2 * 4;
        R0[2*c2]   = __shfl_xor(h ? P0[t4]     : P0[t4 + 2], 32);
        R0[2*c2+1] = __shfl_xor(h ? P0[t4 + 1] : P0[t4 + 3], 32);
        R1[2*c2]   = __shfl_xor(h ? P1[t4]     : P1[t4 + 2], 32);
        R1[2*c2+1] = __shfl_xor(h ? P1[t4 + 1] : P1[t4 + 3], 32);
    }
    #pragma unroll
    for (int c2 = 0; c2 < 2; ++c2) {
        const int t4 = c2 * 4;
        half8 B0 = h ? mk_frag(R0[2*c2], R0[2*c2+1], P0[t4 + 2], P0[t4 + 3])
                     : mk_frag(P0[t4], P0[t4 + 1], R0[2*c2], R0[2*c2+1]);
        half8 B1 = h ? mk_frag(R1[2*c2], R1[2*c2+1], P1[t4 + 2], P1[t4 + 3])
                     : mk_frag(P1[t4], P1[t4 + 1], R1[2*c2], R1[2*c2+1]);
        F00 = __builtin_amdgcn_mfma_f32_32x32x16_f16(G2[2*c2],     B0, F00, 0, 0, 0);
        F01 = __builtin_amdgcn_mfma_f32_32x32x16_f16(G2[2*c2 + 1], B0, F01, 0, 0, 0);
        F10 = __builtin_amdgcn_mfma_f32_32x32x16_f16(G2[2*c2],     B1, F10, 0, 0, 0);
        F11 = __builtin_amdgcn_mfma_f32_32x32x16_f16(G2[2*c2 + 1], B1, F11, 0, 0, 0);
    }
}

// ---- shared body: X phase + main loop + epilogue (used by coop and 2-kernel paths) ----
__device__ __forceinline__ void corr_body(const float* __restrict__ x,
                                          const unsigned char* __restrict__ gimg,
                                          float* __restrict__ out,
                                          float (*Xs)[68],
                                          int tid, int lane, int wid, int team,
                                          int tw, int l31, int h, int n, int lb)
{
    // ---- X tile (256 rows) -> LDS fp32, build both Xf sets ----
    half8 Xf0[4], Xf1[4];
    {
        const int xr = tid >> 1;                   // row 0..255
        const int xh = tid & 1;
        const float* xsrc = x + (size_t)(lb * 256 + xr) * ND + n * D_DIM;
        #pragma unroll
        for (int j = 0; j < 8; ++j) {
            const int f4i = xh * 8 + j;
            *(float4*)&Xs[xr][4 * f4i] = *(const float4*)(xsrc + 4 * f4i);
        }
        __syncthreads();
        const int rl0 = tw * 64 + l31;
        const int rl1 = rl0 + 32;
        #pragma unroll
        for (int kk = 0; kk < 4; ++kk) {
            float4 f1 = *(const float4*)&Xs[rl0][16 * kk + 8 * h];
            float4 f2 = *(const float4*)&Xs[rl0][16 * kk + 8 * h + 4];
            Xf0[kk] = mk_frag(pkh2(f1.x, f1.y), pkh2(f1.z, f1.w),
                              pkh2(f2.x, f2.y), pkh2(f2.z, f2.w));
            float4 f3 = *(const float4*)&Xs[rl1][16 * kk + 8 * h];
            float4 f4v = *(const float4*)&Xs[rl1][16 * kk + 8 * h + 4];
            Xf1[kk] = mk_frag(pkh2(f3.x, f3.y), pkh2(f3.z, f3.w),
                              pkh2(f4v.x, f4v.y), pkh2(f4v.z, f4v.w));
        }
        __syncthreads();   // Xs reads done before epilogue overlay reuse
    }

    floatx16 F00, F01, F10, F11;   // [lh][d-half] accumulators
    #pragma unroll
    for (int i = 0; i < 16; ++i) { F00[i] = 0.0f; F01[i] = 0.0f;
                                   F10[i] = 0.0f; F11[i] = 0.0f; }

    // ---- main loop: 16 tiles, even/odd register double-buffer, zero barriers ----
    half8 AkE[4], G2E[4], AkO[4], G2O[4];
    load_frags(gimg, team, lane, AkE, G2E);                       // tile 0
    for (int ot = 0; ot < 16; ot += 2) {
        load_frags(gimg + (size_t)(ot + 1) * IMG_BYTES, team, lane, AkO, G2O);
        compute_tile(AkE, G2E, Xf0, Xf1, h, F00, F01, F10, F11);  // tile ot
        if (ot + 2 < 16)
            load_frags(gimg + (size_t)(ot + 2) * IMG_BYTES, team, lane, AkE, G2E);
        compute_tile(AkO, G2O, Xf0, Xf1, h, F00, F01, F10, F11);  // tile ot+1
    }

    // ---- epilogue: team combine via LDS overlay, then direct store ----
    if (team == 1) {
        #pragma unroll
        for (int lh = 0; lh < 2; ++lh) {
            const int row = tw * 64 + lh * 32 + l31;
            const floatx16& A = lh ? F10 : F00;
            const floatx16& Bq = lh ? F11 : F01;
            #pragma unroll
            for (int q = 0; q < 4; ++q) {
                float4 a; a.x = A[4*q]; a.y = A[4*q+1]; a.z = A[4*q+2]; a.w = A[4*q+3];
                *(float4*)&Xs[row][8*q + 4*h] = a;            // d 0..31
                float4 b2; b2.x = Bq[4*q]; b2.y = Bq[4*q+1]; b2.z = Bq[4*q+2]; b2.w = Bq[4*q+3];
                *(float4*)&Xs[row][32 + 8*q + 4*h] = b2;      // d 32..63
            }
        }
    }
    __syncthreads();
    if (team == 0) {
        #pragma unroll
        for (int lh = 0; lh < 2; ++lh) {
            const int row = tw * 64 + lh * 32 + l31;
            const floatx16& A = lh ? F10 : F00;
            const floatx16& Bq = lh ? F11 : F01;
            float* op = out + (size_t)(lb * 256 + row) * ND + n * D_DIM;
            #pragma unroll
            for (int q = 0; q < 4; ++q) {
                float4 t0 = *(const float4*)&Xs[row][8*q + 4*h];
                float4 a; a.x = A[4*q]   + t0.x; a.y = A[4*q+1] + t0.y;
                          a.z = A[4*q+2] + t0.z; a.w = A[4*q+3] + t0.w;
                *(float4*)(op + 8*q + 4*h) = a;               // d 0..31
                float4 t1 = *(const float4*)&Xs[row][32 + 8*q + 4*h];
                float4 b2; b2.x = Bq[4*q]   + t1.x; b2.y = Bq[4*q+1] + t1.y;
                           b2.z = Bq[4*q+2] + t1.z; b2.w = Bq[4*q+3] + t1.w;
                *(float4*)(op + 32 + 8*q + 4*h) = b2;         // d 32..63
            }
        }
    }
}

// ====== cooperative kernel: pack (4 tiles/block) + grid.sync + r10 body ======
__global__ void __launch_bounds__(512, 1)
corr_coop(const float* __restrict__ x, const float* __restrict__ up,
          unsigned char* __restrict__ img, float* __restrict__ out)
{
    __shared__ __align__(16) float Xs[256][68];   // 69632 B: X overlay + F-combine

    const int tid  = threadIdx.x;        // 0..511
    const int lane = tid & 63;
    const int wid  = tid >> 6;           // 0..7
    const int team = wid >> 2;
    const int tw   = wid & 3;
    const int l31  = lane & 31;
    const int h    = lane >> 5;
    const int n    = blockIdx.x;         // same n -> same XCD (bid%8 = n%8)
    const int lb   = blockIdx.y;         // L-tile of 256 rows; also pack quarter

    // ---- phase A: pack tiles lb*4 .. lb*4+3 of this n into the ws image ----
    {
        const int ttid = tid & 255;
        const int g    = tid >> 8;       // 0/1: tile pair member
        const int r8   = ttid >> 4;
        const int c    = ttid & 15;
        const float* ubase = up + (size_t)n * D_DIM;
        #pragma unroll
        for (int rd = 0; rd < 2; ++rd) {
            const int ot = lb * 4 + 2 * rd + g;
            float4 va[2], vb[2];
            load_tile(ubase, ot, r8, c, va, vb);
            pack_frag_image(img + (size_t)(n * 16 + ot) * IMG_BYTES, r8, c, va, vb);
        }
    }
    __threadfence();   // publish image writes device-wide before grid sync
    cooperative_groups::this_grid().sync();

    // ---- phase B: proven r10 body ----
    corr_body(x, img + (size_t)n * 16 * IMG_BYTES, out, Xs,
              tid, lane, wid, team, tw, l31, h, n, lb);
}

// ====== two-kernel fallback body (r10 verbatim, via corr_body) ======
__global__ void __launch_bounds__(512, 2)
corr_kernel_w(const float* __restrict__ x, const unsigned char* __restrict__ img,
              float* __restrict__ out)
{
    __shared__ __align__(16) float Xs[256][68];
    const int tid  = threadIdx.x;
    const int lane = tid & 63;
    const int wid  = tid >> 6;
    const int team = wid >> 2;
    const int tw   = wid & 3;
    const int l31  = lane & 31;
    const int h    = lane >> 5;
    const int n    = blockIdx.x;
    const int lb   = blockIdx.y;
    corr_body(x, img + (size_t)n * 16 * IMG_BYTES, out, Xs,
              tid, lane, wid, team, tw, l31, h, n, lb);
}

// ================= fallback (round-3 chassis, verbatim): used if ws too small =================
__global__ void __launch_bounds__(512, 4)
corr_kernel_fb(const float* __restrict__ x, const float* __restrict__ up,
               float* __restrict__ out)
{
    __shared__ __align__(16) unsigned char smem[4 * BUF_STRIDE_FB];

    const int tid  = threadIdx.x;
    const int lane = tid & 63;
    const int wid  = tid >> 6;
    const int team = wid >> 2;
    const int tw   = wid & 3;
    const int l31  = lane & 31;
    const int h    = lane >> 5;
    const int ttid = tid & 255;
    const int r8   = ttid >> 4;
    const int c    = ttid & 15;
    const int n    = blockIdx.x;
    const int lb   = blockIdx.y;
    const int lw   = lb * 128 + tw * 32 + l31;

    const float* ubase = up + (size_t)n * D_DIM;
    const int ob = team * NT;
    unsigned char* tsmem = smem + team * 2 * BUF_STRIDE_FB;

    float4 va[2], vb[2];
    load_tile(ubase, ob + 0, r8, c, va, vb);

    half8 Xf[4];
    {
        float (*Xs)[68] = (float (*)[68])smem;
        const int xr = tid >> 2;
        const int xq = tid & 3;
        const float* xsrc = x + (size_t)(lb * 128 + xr) * ND + n * D_DIM;
        #pragma unroll
        for (int j = 0; j < 4; ++j) {
            const int f4i = xq * 4 + j;
            *(float4*)&Xs[xr][4 * f4i] = *(const float4*)(xsrc + 4 * f4i);
        }
        __syncthreads();
        const int rl = tw * 32 + l31;
        #pragma unroll
        for (int kk = 0; kk < 4; ++kk) {
            float4 f1 = *(const float4*)&Xs[rl][16 * kk + 8 * h];
            float4 f2 = *(const float4*)&Xs[rl][16 * kk + 8 * h + 4];
            Xf[kk] = mk_frag(pkh2(f1.x, f1.y), pkh2(f1.z, f1.w),
                             pkh2(f2.x, f2.y), pkh2(f2.z, f2.w));
        }
        __syncthreads();
    }

    #pragma unroll
    for (int j = 0; j < 2; ++j) {
        uint16_t (*Ub)[72]  = (uint16_t (*)[72])(tsmem);
        uint32_t (*Ut2)[68] = (uint32_t (*)[68])(tsmem + 9216);
        *(uint2*)&Ub[2*r8 + 32*j][4*c] =
            make_uint2(pkh2(va[j].x, va[j].y), pkh2(va[j].z, va[j].w));
        *(uint2*)&Ub[2*r8 + 32*j + 1][4*c] =
            make_uint2(pkh2(vb[j].x, vb[j].y), pkh2(vb[j].z, vb[j].w));
        *(uint4*)&Ut2[r8 + 16*j][4*c] =
            make_uint4(pkh2(va[j].x, vb[j].x), pkh2(va[j].y, vb[j].y),
                       pkh2(va[j].z, vb[j].z), pkh2(va[j].w, vb[j].w));
    }
    load_tile(ubase, ob + 1, r8, c, va, vb);
    __syncthreads();

    floatx16 F0, F1;
    #pragma unroll
    for (int i = 0; i < 16; ++i) { F0[i] = 0.0f; F1[i] = 0.0f; }

    for (int ot = 0; ot < NT; ++ot) {
        const int b = ot & 1;
        uint16_t (*Ub)[72]   = (uint16_t (*)[72])(tsmem + b * BUF_STRIDE_FB);
        const uint32_t* utp  = (const uint32_t*)(tsmem + b * BUF_STRIDE_FB + 9216);
        uint16_t (*Ubn)[72]  = (uint16_t (*)[72])(tsmem + (b ^ 1) * BUF_STRIDE_FB);
        uint32_t (*Ut2n)[68] = (uint32_t (*)[68])(tsmem + (b ^ 1) * BUF_STRIDE_FB + 9216);

        half8 A0k[4], A1k[4];
        #pragma unroll
        for (int kk = 0; kk < 4; ++kk) {
            A0k[kk] = *(const half8*)&Ub[l31][16 * kk + 8 * h];
            A1k[kk] = *(const half8*)&Ub[32 + l31][16 * kk + 8 * h];
        }

        if (ot + 1 < NT) {
            #pragma unroll
            for (int j = 0; j < 2; ++j) {
                *(uint2*)&Ubn[2*r8 + 32*j][4*c] =
                    make_uint2(pkh2(va[j].x, va[j].y), pkh2(va[j].z, va[j].w));
                *(uint2*)&Ubn[2*r8 + 32*j + 1][4*c] =
                    make_uint2(pkh2(vb[j].x, vb[j].y), pkh2(vb[j].z, vb[j].w));
                *(uint4*)&Ut2n[r8 + 16*j][4*c] =
                    make_uint4(pkh2(va[j].x, vb[j].x), pkh2(va[j].y, vb[j].y),
                               pkh2(va[j].z, vb[j].z), pkh2(va[j].w, vb[j].w));
            }
        }
        if (ot + 2 < NT)
            load_tile(ubase, ob + ot + 2, r8, c, va, vb);

        floatx16 S0, S1;
        #pragma unroll
        for (int i = 0; i < 16; ++i) { S0[i] = 0.0f; S1[i] = 0.0f; }
        #pragma unroll
        for (int kk = 0; kk < 4; ++kk) {
            S0 = __builtin_amdgcn_mfma_f32_32x32x16_f16(A0k[kk], Xf[kk], S0, 0, 0, 0);
            S1 = __builtin_amdgcn_mfma_f32_32x32x16_f16(A1k[kk], Xf[kk], S1, 0, 0, 0);
        }

        uint32_t P[16];
        #pragma unroll
        for (int m = 0; m < 8; ++m) P[m]     = psig(S0[2*m], S0[2*m+1]);
        #pragma unroll
        for (int m = 0; m < 8; ++m) P[8 + m] = psig(S1[2*m], S1[2*m+1]);

        uint32_t R[8];
        #pragma unroll
        for (int c2 = 0; c2 < 4; ++c2) {
            const uint32_t* Q = P + (c2 >> 1) * 8;
            const int t4 = (c2 & 1) * 4;
            R[2*c2]   = __shfl_xor(h ? Q[t4]     : Q[t4 + 2], 32);
            R[2*c2+1] = __shfl_xor(h ? Q[t4 + 1] : Q[t4 + 3], 32);
        }
        #pragma unroll
        for (int c2 = 0; c2 < 4; ++c2) {
            const uint32_t* Q = P + (c2 >> 1) * 8;
            const int t4 = (c2 & 1) * 4;
            half8 B = h ? mk_frag(R[2*c2], R[2*c2+1], Q[t4 + 2], Q[t4 + 3])
                        : mk_frag(Q[t4], Q[t4 + 1], R[2*c2], R[2*c2+1]);
            const int opb = 8 * c2 + 4 * h;
            uint32_t a0[4], a1[4];
            #pragma unroll
            for (int k = 0; k < 4; ++k) {
                a0[k] = utp[(opb + k) * 68 + l31];
                a1[k] = utp[(opb + k) * 68 + 32 + l31];
            }
            half8 A0 = mk_frag(a0[0], a0[1], a0[2], a0[3]);
            half8 A1 = mk_frag(a1[0], a1[1], a1[2], a1[3]);
            F0 = __builtin_amdgcn_mfma_f32_32x32x16_f16(A0, B, F0, 0, 0, 0);
            F1 = __builtin_amdgcn_mfma_f32_32x32x16_f16(A1, B, F1, 0, 0, 0);
        }
        __syncthreads();
    }

    {
        float (*Fs)[68] = (float (*)[68])smem;
        const int row = tw * 32 + l31;
        if (team == 1) {
            #pragma unroll
            for (int q = 0; q < 4; ++q) {
                float4 a; a.x = F0[4*q]; a.y = F0[4*q+1]; a.z = F0[4*q+2]; a.w = F0[4*q+3];
                *(float4*)&Fs[row][8*q + 4*h] = a;
                float4 bq; bq.x = F1[4*q]; bq.y = F1[4*q+1]; bq.z = F1[4*q+2]; bq.w = F1[4*q+3];
                *(float4*)&Fs[row][32 + 8*q + 4*h] = bq;
            }
        }
        __syncthreads();
        if (team == 0) {
            float* op = out + (size_t)lw * ND + n * D_DIM;
            #pragma unroll
            for (int q = 0; q < 4; ++q) {
                float4 t0 = *(const float4*)&Fs[row][8*q + 4*h];
                float4 a; a.x = F0[4*q]   + t0.x; a.y = F0[4*q+1] + t0.y;
                          a.z = F0[4*q+2] + t0.z; a.w = F0[4*q+3] + t0.w;
                *(float4*)(op + 8*q + 4*h) = a;
                float4 t1 = *(const float4*)&Fs[row][32 + 8*q + 4*h];
                float4 bq; bq.x = F1[4*q]   + t1.x; bq.y = F1[4*q+1] + t1.y;
                           bq.z = F1[4*q+2] + t1.z; bq.w = F1[4*q+3] + t1.w;
                *(float4*)(op + 32 + 8*q + 4*h) = bq;
            }
        }
    }
}

extern "C" void kernel_launch(void* const* d_in, const int* in_sizes, int n_in,
                              void* d_out, int out_size, void* d_ws, size_t ws_size,
                              hipStream_t stream)
{
    const float* x  = (const float*)d_in[0];
    const float* up = (const float*)d_in[1];
    float* out      = (float*)d_out;

    if (d_ws != nullptr && ws_size >= WS_NEEDED) {
        unsigned char* img = (unsigned char*)d_ws;
        void* args[] = { (void*)&x, (void*)&up, (void*)&img, (void*)&out };
        hipError_t e = hipLaunchCooperativeKernel(
            reinterpret_cast<void*>(corr_coop),
            dim3(N_DIM, L_DIM / 256), dim3(512), args, 0, stream);
        if (e != hipSuccess) {
            // cooperative path unavailable: fall back to the r10 two-kernel pipeline
            conv_kernel<<<dim3(N_DIM, 16), dim3(256), 0, stream>>>(up, img);
            corr_kernel_w<<<dim3(N_DIM, L_DIM / 256), dim3(512), 0, stream>>>(x, img, out);
        }
    } else {
        corr_kernel_fb<<<dim3(N_DIM, L_DIM / 128), dim3(512), 0, stream>>>(x, up, out);
    }
}

// Round 12
// 119.576 us; speedup vs baseline: 1.8156x; 1.8156x over previous
//
#include <hip/hip_runtime.h>
#include <stdint.h>

#define L_DIM 1024
#define N_DIM 64
#define D_DIM 64
#define O_DIM 1024
#define ND    4096              // slice stride (floats) for x / upfold rows
#define NT    8                 // O tiles per team (fallback kernel)

typedef float    floatx16 __attribute__((ext_vector_type(16)));
typedef _Float16 half8    __attribute__((ext_vector_type(8)));
typedef _Float16 h2       __attribute__((ext_vector_type(2)));
typedef __fp16   fp16x2   __attribute__((ext_vector_type(2)));

// ---------- fragment-order U image (r9-verified layout) ----------
// per 64-o tile (16384 B):
//   G1 [team t][kk]          : 2x4 chunks of 1024 B at  t*4096 + kk*1024
//       lane p, 16B = Ub[t*32 + (p&31)][d = 16*kk + 8*(p>>5) .. +8]   (8 f16)
//   G2 [t][c2][r]  (base 8192): 2x2x2 chunks of 1024 B at 8192 + t*4096 + c2*2048 + r*1024
//       lane p, 16B = UtT[r*32 + (p&31)][op = t*16 + 8*c2 + 4*(p>>5) .. +4]  (4 u32 o-pairs)
#define IMG_BYTES 16384
#define WS_NEEDED ((size_t)N_DIM * 16 * IMG_BYTES)   // 16 MiB

#define BUF_STRIDE_FB 17920     // fallback kernel: Ub 9216 B + Ut2 8704 B

__device__ __forceinline__ uint32_t pkh2(float a, float b) {
    fp16x2 p = __builtin_amdgcn_cvt_pkrtz(a, b);   // v_cvt_pkrtz_f16_f32
    return __builtin_bit_cast(uint32_t, p);
}

__device__ __forceinline__ half8 mk_frag(uint32_t a, uint32_t b, uint32_t c, uint32_t d) {
    union { uint32_t u[4]; half8 v; } U;
    U.u[0] = a; U.u[1] = b; U.u[2] = c; U.u[3] = d;
    return U.v;
}

// sigmoid(s/8) - 0.5 = 0.5*tanh(s/16), odd poly in v=(s/16)^2, packed fp16.
__device__ __forceinline__ uint32_t psig(float s0, float s1) {
    const h2 HI = {(_Float16)41.6f,        (_Float16)41.6f};
    const h2 LO = {(_Float16)-41.6f,       (_Float16)-41.6f};
    const h2 SC = {(_Float16)0.0625f,      (_Float16)0.0625f};
    const h2 C0 = {(_Float16)0.03099238f,  (_Float16)0.03099238f};
    const h2 C1 = {(_Float16)-0.00842090f, (_Float16)-0.00842090f};
    const h2 C2 = {(_Float16)0.00151845f,  (_Float16)0.00151845f};
    const h2 C3 = {(_Float16)-1.02197e-4f, (_Float16)-1.02197e-4f};
    h2 s = __builtin_bit_cast(h2, pkh2(s0, s1));
    s = __builtin_elementwise_min(s, HI);
    s = __builtin_elementwise_max(s, LO);
    h2 ha = s * SC;
    h2 v  = ha * ha;
    h2 w  = C2 + v * C3;
    w     = C1 + v * w;
    w     = C0 + v * w;
    h2 f  = s * w;
    return __builtin_bit_cast(uint32_t, f);
}

// Coalesced U tile load: thread (r8, c) takes rows 2*r8+32j (va)/+1 (vb).
__device__ __forceinline__ void load_tile(const float* ubase, int ot,
                                          int r8, int c, float4* va, float4* vb) {
    const float* pr = ubase + (size_t)(ot * 64 + 2 * r8) * ND + 4 * c;
    #pragma unroll
    for (int j = 0; j < 2; ++j) {
        va[j] = *(const float4*)(pr + (size_t)(32 * j) * ND);
        vb[j] = *(const float4*)(pr + (size_t)(32 * j) * ND + ND);
    }
}

// ---- pack one tile's registers into the fragment-order image (r9-verified) ----
__device__ __forceinline__ void pack_frag_image(unsigned char* tb, int r8, int c,
                                                const float4* va, const float4* vb)
{
    // G1
    const int kk = c >> 2;
    const int hh = (c >> 1) & 1;
    const int co = (c & 1) * 8;
    #pragma unroll
    for (int j = 0; j < 2; ++j) {
        const int o0 = 2 * r8 + 32 * j;
        unsigned char* g1 = tb + j * 4096 + kk * 1024 + co;
        *(uint2*)(g1 + ((o0 & 31) + 32 * hh) * 16) =
            make_uint2(pkh2(va[j].x, va[j].y), pkh2(va[j].z, va[j].w));
        *(uint2*)(g1 + (((o0 + 1) & 31) + 32 * hh) * 16) =
            make_uint2(pkh2(vb[j].x, vb[j].y), pkh2(vb[j].z, vb[j].w));
    }
    // G2
    #pragma unroll
    for (int j = 0; j < 2; ++j) {
        const int op   = r8 + 16 * j;
        const int g    = op >> 2;
        const int slot = op & 3;
        const int t2   = g >> 2;
        const int c22  = (g >> 1) & 1;
        const int h2i  = g & 1;
        const float* pa = (const float*)&va[j];
        const float* pb = (const float*)&vb[j];
        #pragma unroll
        for (int col = 0; col < 4; ++col) {
            const int d    = 4 * c + col;
            const int r    = d >> 5;
            const int lane = (d & 31) + 32 * h2i;
            *(uint32_t*)(tb + 8192 + t2 * 4096 + c22 * 2048 + r * 1024
                         + lane * 16 + slot * 4) = pkh2(pa[col], pb[col]);
        }
    }
}

// ---- per-tile fragment loads: 8 lane-contiguous dwordx4 ----
__device__ __forceinline__ void load_frags(const unsigned char* tb, int team, int lane,
                                           half8* Ak, half8* G2) {
    const unsigned char* g1 = tb + team * 4096 + (size_t)lane * 16;
    #pragma unroll
    for (int kk = 0; kk < 4; ++kk)
        Ak[kk] = *(const half8*)(g1 + kk * 1024);
    const unsigned char* g2 = tb + 8192 + team * 4096 + (size_t)lane * 16;
    #pragma unroll
    for (int i = 0; i < 4; ++i)
        G2[i] = *(const half8*)(g2 + i * 1024);   // [0]=A0c0 [1]=A1c0 [2]=A0c1 [3]=A1c1
}

// ---- per-tile compute: both l-halves share the U fragments ----
__device__ __forceinline__ void compute_tile(const half8* Ak, const half8* G2,
                                             const half8* Xf0, const half8* Xf1, int h,
                                             floatx16& F00, floatx16& F01,
                                             floatx16& F10, floatx16& F11)
{
    floatx16 S0, S1;
    #pragma unroll
    for (int i = 0; i < 16; ++i) { S0[i] = 0.0f; S1[i] = 0.0f; }
    #pragma unroll
    for (int kk = 0; kk < 4; ++kk) {
        S0 = __builtin_amdgcn_mfma_f32_32x32x16_f16(Ak[kk], Xf0[kk], S0, 0, 0, 0);
        S1 = __builtin_amdgcn_mfma_f32_32x32x16_f16(Ak[kk], Xf1[kk], S1, 0, 0, 0);
    }

    uint32_t P0[8], P1[8];
    #pragma unroll
    for (int m = 0; m < 8; ++m) { P0[m] = psig(S0[2*m], S0[2*m+1]);
                                  P1[m] = psig(S1[2*m], S1[2*m+1]); }

    uint32_t R0[4], R1[4];
    #pragma unroll
    for (int c2 = 0; c2 < 2; ++c2) {
        const int t4 = c2 * 4;
        R0[2*c2]   = __shfl_xor(h ? P0[t4]     : P0[t4 + 2], 32);
        R0[2*c2+1] = __shfl_xor(h ? P0[t4 + 1] : P0[t4 + 3], 32);
        R1[2*c2]   = __shfl_xor(h ? P1[t4]     : P1[t4 + 2], 32);
        R1[2*c2+1] = __shfl_xor(h ? P1[t4 + 1] : P1[t4 + 3], 32);
    }
    #pragma unroll
    for (int c2 = 0; c2 < 2; ++c2) {
        const int t4 = c2 * 4;
        half8 B0 = h ? mk_frag(R0[2*c2], R0[2*c2+1], P0[t4 + 2], P0[t4 + 3])
                     : mk_frag(P0[t4], P0[t4 + 1], R0[2*c2], R0[2*c2+1]);
        half8 B1 = h ? mk_frag(R1[2*c2], R1[2*c2+1], P1[t4 + 2], P1[t4 + 3])
                     : mk_frag(P1[t4], P1[t4 + 1], R1[2*c2], R1[2*c2+1]);
        F00 = __builtin_amdgcn_mfma_f32_32x32x16_f16(G2[2*c2],     B0, F00, 0, 0, 0);
        F01 = __builtin_amdgcn_mfma_f32_32x32x16_f16(G2[2*c2 + 1], B0, F01, 0, 0, 0);
        F10 = __builtin_amdgcn_mfma_f32_32x32x16_f16(G2[2*c2],     B1, F10, 0, 0, 0);
        F11 = __builtin_amdgcn_mfma_f32_32x32x16_f16(G2[2*c2 + 1], B1, F11, 0, 0, 0);
    }
}

// ---- shared body: X phase + main loop + epilogue (r10-verified) ----
__device__ __forceinline__ void corr_body(const float* __restrict__ x,
                                          const unsigned char* __restrict__ gimg,
                                          float* __restrict__ out,
                                          float (*Xs)[68],
                                          int tid, int lane, int wid, int team,
                                          int tw, int l31, int h, int n, int lb)
{
    // ---- X tile (256 rows) -> LDS fp32, build both Xf sets ----
    half8 Xf0[4], Xf1[4];
    {
        const int xr = tid >> 1;                   // row 0..255
        const int xh = tid & 1;
        const float* xsrc = x + (size_t)(lb * 256 + xr) * ND + n * D_DIM;
        #pragma unroll
        for (int j = 0; j < 8; ++j) {
            const int f4i = xh * 8 + j;
            *(float4*)&Xs[xr][4 * f4i] = *(const float4*)(xsrc + 4 * f4i);
        }
        __syncthreads();   // also drains this thread's pack writes (waitcnt 0)
        const int rl0 = tw * 64 + l31;
        const int rl1 = rl0 + 32;
        #pragma unroll
        for (int kk = 0; kk < 4; ++kk) {
            float4 f1 = *(const float4*)&Xs[rl0][16 * kk + 8 * h];
            float4 f2 = *(const float4*)&Xs[rl0][16 * kk + 8 * h + 4];
            Xf0[kk] = mk_frag(pkh2(f1.x, f1.y), pkh2(f1.z, f1.w),
                              pkh2(f2.x, f2.y), pkh2(f2.z, f2.w));
            float4 f3 = *(const float4*)&Xs[rl1][16 * kk + 8 * h];
            float4 f4v = *(const float4*)&Xs[rl1][16 * kk + 8 * h + 4];
            Xf1[kk] = mk_frag(pkh2(f3.x, f3.y), pkh2(f3.z, f3.w),
                              pkh2(f4v.x, f4v.y), pkh2(f4v.z, f4v.w));
        }
        __syncthreads();   // Xs reads done before epilogue overlay reuse
    }

    floatx16 F00, F01, F10, F11;   // [lh][d-half] accumulators
    #pragma unroll
    for (int i = 0; i < 16; ++i) { F00[i] = 0.0f; F01[i] = 0.0f;
                                   F10[i] = 0.0f; F11[i] = 0.0f; }

    // ---- main loop: 16 tiles, even/odd register double-buffer, zero barriers ----
    half8 AkE[4], G2E[4], AkO[4], G2O[4];
    load_frags(gimg, team, lane, AkE, G2E);                       // tile 0
    for (int ot = 0; ot < 16; ot += 2) {
        load_frags(gimg + (size_t)(ot + 1) * IMG_BYTES, team, lane, AkO, G2O);
        compute_tile(AkE, G2E, Xf0, Xf1, h, F00, F01, F10, F11);  // tile ot
        if (ot + 2 < 16)
            load_frags(gimg + (size_t)(ot + 2) * IMG_BYTES, team, lane, AkE, G2E);
        compute_tile(AkO, G2O, Xf0, Xf1, h, F00, F01, F10, F11);  // tile ot+1
    }

    // ---- epilogue: team combine via LDS overlay, then direct store ----
    if (team == 1) {
        #pragma unroll
        for (int lh = 0; lh < 2; ++lh) {
            const int row = tw * 64 + lh * 32 + l31;
            const floatx16& A = lh ? F10 : F00;
            const floatx16& Bq = lh ? F11 : F01;
            #pragma unroll
            for (int q = 0; q < 4; ++q) {
                float4 a; a.x = A[4*q]; a.y = A[4*q+1]; a.z = A[4*q+2]; a.w = A[4*q+3];
                *(float4*)&Xs[row][8*q + 4*h] = a;            // d 0..31
                float4 b2; b2.x = Bq[4*q]; b2.y = Bq[4*q+1]; b2.z = Bq[4*q+2]; b2.w = Bq[4*q+3];
                *(float4*)&Xs[row][32 + 8*q + 4*h] = b2;      // d 32..63
            }
        }
    }
    __syncthreads();
    if (team == 0) {
        #pragma unroll
        for (int lh = 0; lh < 2; ++lh) {
            const int row = tw * 64 + lh * 32 + l31;
            const floatx16& A = lh ? F10 : F00;
            const floatx16& Bq = lh ? F11 : F01;
            float* op = out + (size_t)(lb * 256 + row) * ND + n * D_DIM;
            #pragma unroll
            for (int q = 0; q < 4; ++q) {
                float4 t0 = *(const float4*)&Xs[row][8*q + 4*h];
                float4 a; a.x = A[4*q]   + t0.x; a.y = A[4*q+1] + t0.y;
                          a.z = A[4*q+2] + t0.z; a.w = A[4*q+3] + t0.w;
                *(float4*)(op + 8*q + 4*h) = a;               // d 0..31
                float4 t1 = *(const float4*)&Xs[row][32 + 8*q + 4*h];
                float4 b2; b2.x = Bq[4*q]   + t1.x; b2.y = Bq[4*q+1] + t1.y;
                           b2.z = Bq[4*q+2] + t1.z; b2.w = Bq[4*q+3] + t1.w;
                *(float4*)(op + 32 + 8*q + 4*h) = b2;         // d 32..63
            }
        }
    }
}

// ====== single kernel: idempotent duplicate pack + r10 body, NO inter-block sync ======
// Each of the 4 lb-blocks of an n packs the full 16-tile image for that n (same
// values to the same ws region: benign identical-value race). A block only reads
// what it wrote itself, after its own barrier — no dependence on other blocks.
__global__ void __launch_bounds__(512, 2)
corr_single(const float* __restrict__ x, const float* __restrict__ up,
            unsigned char* img, float* __restrict__ out)
{
    __shared__ __align__(16) float Xs[256][68];   // 69632 B: X overlay + F-combine

    const int tid  = threadIdx.x;        // 0..511
    const int lane = tid & 63;
    const int wid  = tid >> 6;           // 0..7
    const int team = wid >> 2;
    const int tw   = wid & 3;
    const int l31  = lane & 31;
    const int h    = lane >> 5;
    const int n    = blockIdx.x;         // same n -> same XCD (bid%8 = n%8)
    const int lb   = blockIdx.y;         // L-tile of 256 rows

    // ---- phase A: pack ALL 16 tiles of this n (duplicated across lb, idempotent) ----
    {
        const int ttid = tid & 255;
        const int g    = tid >> 8;       // threads 0-255: even tiles, 256-511: odd
        const int r8   = ttid >> 4;
        const int c    = ttid & 15;
        const float* ubase = up + (size_t)n * D_DIM;
        unsigned char* nimg = img + (size_t)n * 16 * IMG_BYTES;
        #pragma unroll 2
        for (int rd = 0; rd < 8; ++rd) {
            const int ot = 2 * rd + g;
            float4 va[2], vb[2];
            load_tile(ubase, ot, r8, c, va, vb);
            pack_frag_image(nimg + (size_t)ot * IMG_BYTES, r8, c, va, vb);
        }
    }
    // visibility: corr_body's first __syncthreads (waitcnt vmcnt(0) + barrier)
    // drains every thread's image writes before any thread reads the image.

    // ---- phase B: proven r10 body ----
    corr_body(x, img + (size_t)n * 16 * IMG_BYTES, out, Xs,
              tid, lane, wid, team, tw, l31, h, n, lb);
}

// ================= fallback (round-3 chassis, verbatim): used if ws too small =================
__global__ void __launch_bounds__(512, 4)
corr_kernel_fb(const float* __restrict__ x, const float* __restrict__ up,
               float* __restrict__ out)
{
    __shared__ __align__(16) unsigned char smem[4 * BUF_STRIDE_FB];

    const int tid  = threadIdx.x;
    const int lane = tid & 63;
    const int wid  = tid >> 6;
    const int team = wid >> 2;
    const int tw   = wid & 3;
    const int l31  = lane & 31;
    const int h    = lane >> 5;
    const int ttid = tid & 255;
    const int r8   = ttid >> 4;
    const int c    = ttid & 15;
    const int n    = blockIdx.x;
    const int lb   = blockIdx.y;
    const int lw   = lb * 128 + tw * 32 + l31;

    const float* ubase = up + (size_t)n * D_DIM;
    const int ob = team * NT;
    unsigned char* tsmem = smem + team * 2 * BUF_STRIDE_FB;

    float4 va[2], vb[2];
    load_tile(ubase, ob + 0, r8, c, va, vb);

    half8 Xf[4];
    {
        float (*Xs)[68] = (float (*)[68])smem;
        const int xr = tid >> 2;
        const int xq = tid & 3;
        const float* xsrc = x + (size_t)(lb * 128 + xr) * ND + n * D_DIM;
        #pragma unroll
        for (int j = 0; j < 4; ++j) {
            const int f4i = xq * 4 + j;
            *(float4*)&Xs[xr][4 * f4i] = *(const float4*)(xsrc + 4 * f4i);
        }
        __syncthreads();
        const int rl = tw * 32 + l31;
        #pragma unroll
        for (int kk = 0; kk < 4; ++kk) {
            float4 f1 = *(const float4*)&Xs[rl][16 * kk + 8 * h];
            float4 f2 = *(const float4*)&Xs[rl][16 * kk + 8 * h + 4];
            Xf[kk] = mk_frag(pkh2(f1.x, f1.y), pkh2(f1.z, f1.w),
                             pkh2(f2.x, f2.y), pkh2(f2.z, f2.w));
        }
        __syncthreads();
    }

    #pragma unroll
    for (int j = 0; j < 2; ++j) {
        uint16_t (*Ub)[72]  = (uint16_t (*)[72])(tsmem);
        uint32_t (*Ut2)[68] = (uint32_t (*)[68])(tsmem + 9216);
        *(uint2*)&Ub[2*r8 + 32*j][4*c] =
            make_uint2(pkh2(va[j].x, va[j].y), pkh2(va[j].z, va[j].w));
        *(uint2*)&Ub[2*r8 + 32*j + 1][4*c] =
            make_uint2(pkh2(vb[j].x, vb[j].y), pkh2(vb[j].z, vb[j].w));
        *(uint4*)&Ut2[r8 + 16*j][4*c] =
            make_uint4(pkh2(va[j].x, vb[j].x), pkh2(va[j].y, vb[j].y),
                       pkh2(va[j].z, vb[j].z), pkh2(va[j].w, vb[j].w));
    }
    load_tile(ubase, ob + 1, r8, c, va, vb);
    __syncthreads();

    floatx16 F0, F1;
    #pragma unroll
    for (int i = 0; i < 16; ++i) { F0[i] = 0.0f; F1[i] = 0.0f; }

    for (int ot = 0; ot < NT; ++ot) {
        const int b = ot & 1;
        uint16_t (*Ub)[72]   = (uint16_t (*)[72])(tsmem + b * BUF_STRIDE_FB);
        const uint32_t* utp  = (const uint32_t*)(tsmem + b * BUF_STRIDE_FB + 9216);
        uint16_t (*Ubn)[72]  = (uint16_t (*)[72])(tsmem + (b ^ 1) * BUF_STRIDE_FB);
        uint32_t (*Ut2n)[68] = (uint32_t (*)[68])(tsmem + (b ^ 1) * BUF_STRIDE_FB + 9216);

        half8 A0k[4], A1k[4];
        #pragma unroll
        for (int kk = 0; kk < 4; ++kk) {
            A0k[kk] = *(const half8*)&Ub[l31][16 * kk + 8 * h];
            A1k[kk] = *(const half8*)&Ub[32 + l31][16 * kk + 8 * h];
        }

        if (ot + 1 < NT) {
            #pragma unroll
            for (int j = 0; j < 2; ++j) {
                *(uint2*)&Ubn[2*r8 + 32*j][4*c] =
                    make_uint2(pkh2(va[j].x, va[j].y), pkh2(va[j].z, va[j].w));
                *(uint2*)&Ubn[2*r8 + 32*j + 1][4*c] =
                    make_uint2(pkh2(vb[j].x, vb[j].y), pkh2(vb[j].z, vb[j].w));
                *(uint4*)&Ut2n[r8 + 16*j][4*c] =
                    make_uint4(pkh2(va[j].x, vb[j].x), pkh2(va[j].y, vb[j].y),
                               pkh2(va[j].z, vb[j].z), pkh2(va[j].w, vb[j].w));
            }
        }
        if (ot + 2 < NT)
            load_tile(ubase, ob + ot + 2, r8, c, va, vb);

        floatx16 S0, S1;
        #pragma unroll
        for (int i = 0; i < 16; ++i) { S0[i] = 0.0f; S1[i] = 0.0f; }
        #pragma unroll
        for (int kk = 0; kk < 4; ++kk) {
            S0 = __builtin_amdgcn_mfma_f32_32x32x16_f16(A0k[kk], Xf[kk], S0, 0, 0, 0);
            S1 = __builtin_amdgcn_mfma_f32_32x32x16_f16(A1k[kk], Xf[kk], S1, 0, 0, 0);
        }

        uint32_t P[16];
        #pragma unroll
        for (int m = 0; m < 8; ++m) P[m]     = psig(S0[2*m], S0[2*m+1]);
        #pragma unroll
        for (int m = 0; m < 8; ++m) P[8 + m] = psig(S1[2*m], S1[2*m+1]);

        uint32_t R[8];
        #pragma unroll
        for (int c2 = 0; c2 < 4; ++c2) {
            const uint32_t* Q = P + (c2 >> 1) * 8;
            const int t4 = (c2 & 1) * 4;
            R[2*c2]   = __shfl_xor(h ? Q[t4]     : Q[t4 + 2], 32);
            R[2*c2+1] = __shfl_xor(h ? Q[t4 + 1] : Q[t4 + 3], 32);
        }
        #pragma unroll
        for (int c2 = 0; c2 < 4; ++c2) {
            const uint32_t* Q = P + (c2 >> 1) * 8;
            const int t4 = (c2 & 1) * 4;
            half8 B = h ? mk_frag(R[2*c2], R[2*c2+1], Q[t4 + 2], Q[t4 + 3])
                        : mk_frag(Q[t4], Q[t4 + 1], R[2*c2], R[2*c2+1]);
            const int opb = 8 * c2 + 4 * h;
            uint32_t a0[4], a1[4];
            #pragma unroll
            for (int k = 0; k < 4; ++k) {
                a0[k] = utp[(opb + k) * 68 + l31];
                a1[k] = utp[(opb + k) * 68 + 32 + l31];
            }
            half8 A0 = mk_frag(a0[0], a0[1], a0[2], a0[3]);
            half8 A1 = mk_frag(a1[0], a1[1], a1[2], a1[3]);
            F0 = __builtin_amdgcn_mfma_f32_32x32x16_f16(A0, B, F0, 0, 0, 0);
            F1 = __builtin_amdgcn_mfma_f32_32x32x16_f16(A1, B, F1, 0, 0, 0);
        }
        __syncthreads();
    }

    {
        float (*Fs)[68] = (float (*)[68])smem;
        const int row = tw * 32 + l31;
        if (team == 1) {
            #pragma unroll
            for (int q = 0; q < 4; ++q) {
                float4 a; a.x = F0[4*q]; a.y = F0[4*q+1]; a.z = F0[4*q+2]; a.w = F0[4*q+3];
                *(float4*)&Fs[row][8*q + 4*h] = a;
                float4 bq; bq.x = F1[4*q]; bq.y = F1[4*q+1]; bq.z = F1[4*q+2]; bq.w = F1[4*q+3];
                *(float4*)&Fs[row][32 + 8*q + 4*h] = bq;
            }
        }
        __syncthreads();
        if (team == 0) {
            float* op = out + (size_t)lw * ND + n * D_DIM;
            #pragma unroll
            for (int q = 0; q < 4; ++q) {
                float4 t0 = *(const float4*)&Fs[row][8*q + 4*h];
                float4 a; a.x = F0[4*q]   + t0.x; a.y = F0[4*q+1] + t0.y;
                          a.z = F0[4*q+2] + t0.z; a.w = F0[4*q+3] + t0.w;
                *(float4*)(op + 8*q + 4*h) = a;
                float4 t1 = *(const float4*)&Fs[row][32 + 8*q + 4*h];
                float4 bq; bq.x = F1[4*q]   + t1.x; bq.y = F1[4*q+1] + t1.y;
                           bq.z = F1[4*q+2] + t1.z; bq.w = F1[4*q+3] + t1.w;
                *(float4*)(op + 32 + 8*q + 4*h) = bq;
            }
        }
    }
}

extern "C" void kernel_launch(void* const* d_in, const int* in_sizes, int n_in,
                              void* d_out, int out_size, void* d_ws, size_t ws_size,
                              hipStream_t stream)
{
    const float* x  = (const float*)d_in[0];
    const float* up = (const float*)d_in[1];
    float* out      = (float*)d_out;

    if (d_ws != nullptr && ws_size >= WS_NEEDED) {
        unsigned char* img = (unsigned char*)d_ws;
        corr_single<<<dim3(N_DIM, L_DIM / 256), dim3(512), 0, stream>>>(x, up, img, out);
    } else {
        corr_kernel_fb<<<dim3(N_DIM, L_DIM / 128), dim3(512), 0, stream>>>(x, up, out);
    }
}

// Round 13
// 112.518 us; speedup vs baseline: 1.9295x; 1.0627x over previous
//
#include <hip/hip_runtime.h>
#include <stdint.h>

#define L_DIM 1024
#define N_DIM 64
#define D_DIM 64
#define O_DIM 1024
#define ND    4096              // slice stride (floats) for x / upfold rows

// ---------- fragment-order U image, LDS-resident (r9-verified layout) ----------
// per 64-o tile (16384 B), tile base TB:
//   G1 chunk (t,kk) at TB + t*4096 + kk*1024:
//     lane q, 16B = U[ot*64 + t*32 + (q&31)][n][d0..d0+8) as f16, d0 = 16*kk + 8*(q>>5)
//   G2 chunk (t,c2,r) at TB + 8192 + t*4096 + c2*2048 + r*1024:
//     lane q, dword m = pkh2(U[ot*64 + 2*(opb+m)][n][d], U[ot*64 + 2*(opb+m)+1][n][d])
//     with opb = t*16 + 8*c2 + 4*(q>>5), d = r*32 + (q&31)
// (byte-identical to the r10-verified global image; bijection op -> (t,c2,h2i,slot)
//  checked against the conv mapping term-by-term)
#define TILE_BYTES 16384
#define HALF_TILES 8
#define IMG_LDS   (HALF_TILES * TILE_BYTES)    // 131072 B -> 1 block/CU

typedef float    floatx16 __attribute__((ext_vector_type(16)));
typedef _Float16 half8    __attribute__((ext_vector_type(8)));
typedef _Float16 h2       __attribute__((ext_vector_type(2)));
typedef __fp16   fp16x2   __attribute__((ext_vector_type(2)));

__device__ __forceinline__ uint32_t pkh2(float a, float b) {
    fp16x2 p = __builtin_amdgcn_cvt_pkrtz(a, b);   // v_cvt_pkrtz_f16_f32
    return __builtin_bit_cast(uint32_t, p);
}

__device__ __forceinline__ half8 mk_frag(uint32_t a, uint32_t b, uint32_t c, uint32_t d) {
    union { uint32_t u[4]; half8 v; } U;
    U.u[0] = a; U.u[1] = b; U.u[2] = c; U.u[3] = d;
    return U.v;
}

// sigmoid(s/8) - 0.5 = 0.5*tanh(s/16), odd poly in v=(s/16)^2, packed fp16.
__device__ __forceinline__ uint32_t psig(float s0, float s1) {
    const h2 HI = {(_Float16)41.6f,        (_Float16)41.6f};
    const h2 LO = {(_Float16)-41.6f,       (_Float16)-41.6f};
    const h2 SC = {(_Float16)0.0625f,      (_Float16)0.0625f};
    const h2 C0 = {(_Float16)0.03099238f,  (_Float16)0.03099238f};
    const h2 C1 = {(_Float16)-0.00842090f, (_Float16)-0.00842090f};
    const h2 C2 = {(_Float16)0.00151845f,  (_Float16)0.00151845f};
    const h2 C3 = {(_Float16)-1.02197e-4f, (_Float16)-1.02197e-4f};
    h2 s = __builtin_bit_cast(h2, pkh2(s0, s1));
    s = __builtin_elementwise_min(s, HI);
    s = __builtin_elementwise_max(s, LO);
    h2 ha = s * SC;
    h2 v  = ha * ha;
    h2 w  = C2 + v * C3;
    w     = C1 + v * w;
    w     = C0 + v * w;
    h2 f  = s * w;
    return __builtin_bit_cast(uint32_t, f);
}

// ---- consumer-mapped pack: wave w packs its G1 chunk and G2 chunk of tile ot ----
// Every LDS write is one dense, conflict-free ds_write_b128 (lane-linear 1KB chunk).
__device__ __forceinline__ void pack_chunks(const float* up_n, int ot, int w, int lane,
                                            unsigned char* tb)
{
    // G1 chunk (t = w>>2, kk = w&3): lane reads 32B contiguous (2 float4) of one U row
    {
        const int t  = w >> 2, kk = w & 3;
        const int ot_row = ot * 64 + t * 32 + (lane & 31);
        const int d0 = 16 * kk + 8 * (lane >> 5);
        const float* src = up_n + (size_t)ot_row * ND + d0;
        float4 f1 = *(const float4*)src;
        float4 f2 = *(const float4*)(src + 4);
        *(uint4*)(tb + t * 4096 + kk * 1024 + lane * 16) =
            make_uint4(pkh2(f1.x, f1.y), pkh2(f1.z, f1.w),
                       pkh2(f2.x, f2.y), pkh2(f2.z, f2.w));
    }
    // G2 chunk (t = w>>2, c2 = (w>>1)&1, r = w&1): 8 dword loads, each wave-instr
    // covers 2 x 128B contiguous row segments (dense lines)
    {
        const int t  = w >> 2, c2 = (w >> 1) & 1, r = w & 1;
        const int d   = r * 32 + (lane & 31);
        const int opb = t * 16 + 8 * c2 + 4 * (lane >> 5);
        const float* sp = up_n + (size_t)(ot * 64 + 2 * opb) * ND + d;
        uint32_t u0 = pkh2(sp[0],                 sp[(size_t)ND]);
        uint32_t u1 = pkh2(sp[(size_t)2 * ND],    sp[(size_t)3 * ND]);
        uint32_t u2 = pkh2(sp[(size_t)4 * ND],    sp[(size_t)5 * ND]);
        uint32_t u3 = pkh2(sp[(size_t)6 * ND],    sp[(size_t)7 * ND]);
        *(uint4*)(tb + 8192 + t * 4096 + c2 * 2048 + r * 1024 + lane * 16) =
            make_uint4(u0, u1, u2, u3);
    }
}

// ---- per-tile fragment loads from LDS: 8 conflict-free ds_read_b128 ----
__device__ __forceinline__ void load_frags(const unsigned char* tb, int team, int lane,
                                           half8* Ak, half8* G2) {
    const unsigned char* g1 = tb + team * 4096 + (size_t)lane * 16;
    #pragma unroll
    for (int kk = 0; kk < 4; ++kk)
        Ak[kk] = *(const half8*)(g1 + kk * 1024);
    const unsigned char* g2 = tb + 8192 + team * 4096 + (size_t)lane * 16;
    #pragma unroll
    for (int i = 0; i < 4; ++i)
        G2[i] = *(const half8*)(g2 + i * 1024);   // [0]=A0c0 [1]=A1c0 [2]=A0c1 [3]=A1c1
}

// ---- per-tile compute (r10-verified): both l-halves share the U fragments ----
__device__ __forceinline__ void compute_tile(const half8* Ak, const half8* G2,
                                             const half8* Xf0, const half8* Xf1, int h,
                                             floatx16& F00, floatx16& F01,
                                             floatx16& F10, floatx16& F11)
{
    floatx16 S0, S1;
    #pragma unroll
    for (int i = 0; i < 16; ++i) { S0[i] = 0.0f; S1[i] = 0.0f; }
    #pragma unroll
    for (int kk = 0; kk < 4; ++kk) {
        S0 = __builtin_amdgcn_mfma_f32_32x32x16_f16(Ak[kk], Xf0[kk], S0, 0, 0, 0);
        S1 = __builtin_amdgcn_mfma_f32_32x32x16_f16(Ak[kk], Xf1[kk], S1, 0, 0, 0);
    }

    uint32_t P0[8], P1[8];
    #pragma unroll
    for (int m = 0; m < 8; ++m) { P0[m] = psig(S0[2*m], S0[2*m+1]);
                                  P1[m] = psig(S1[2*m], S1[2*m+1]); }

    uint32_t R0[4], R1[4];
    #pragma unroll
    for (int c2 = 0; c2 < 2; ++c2) {
        const int t4 = c2 * 4;
        R0[2*c2]   = __shfl_xor(h ? P0[t4]     : P0[t4 + 2], 32);
        R0[2*c2+1] = __shfl_xor(h ? P0[t4 + 1] : P0[t4 + 3], 32);
        R1[2*c2]   = __shfl_xor(h ? P1[t4]     : P1[t4 + 2], 32);
        R1[2*c2+1] = __shfl_xor(h ? P1[t4 + 1] : P1[t4 + 3], 32);
    }
    #pragma unroll
    for (int c2 = 0; c2 < 2; ++c2) {
        const int t4 = c2 * 4;
        half8 B0 = h ? mk_frag(R0[2*c2], R0[2*c2+1], P0[t4 + 2], P0[t4 + 3])
                     : mk_frag(P0[t4], P0[t4 + 1], R0[2*c2], R0[2*c2+1]);
        half8 B1 = h ? mk_frag(R1[2*c2], R1[2*c2+1], P1[t4 + 2], P1[t4 + 3])
                     : mk_frag(P1[t4], P1[t4 + 1], R1[2*c2], R1[2*c2+1]);
        F00 = __builtin_amdgcn_mfma_f32_32x32x16_f16(G2[2*c2],     B0, F00, 0, 0, 0);
        F01 = __builtin_amdgcn_mfma_f32_32x32x16_f16(G2[2*c2 + 1], B0, F01, 0, 0, 0);
        F10 = __builtin_amdgcn_mfma_f32_32x32x16_f16(G2[2*c2],     B1, F10, 0, 0, 0);
        F11 = __builtin_amdgcn_mfma_f32_32x32x16_f16(G2[2*c2 + 1], B1, F11, 0, 0, 0);
    }
}

// ====== single kernel: LDS-resident image, two O-halves, zero in-loop barriers ======
__global__ void __launch_bounds__(512, 2)
corr_lds(const float* __restrict__ x, const float* __restrict__ up,
         float* __restrict__ out)
{
    __shared__ __align__(16) unsigned char simg[IMG_LDS];   // 131072 B, 1 block/CU
    float (*Xs)[68] = (float (*)[68])simg;                  // 69632 B overlay (X / epilogue)

    const int tid  = threadIdx.x;        // 0..511
    const int lane = tid & 63;
    const int wid  = tid >> 6;           // 0..7
    const int team = wid >> 2;           // o-half of each tile
    const int tw   = wid & 3;            // l-group of 64 rows
    const int l31  = lane & 31;
    const int h    = lane >> 5;          // wave half
    const int n    = blockIdx.x;         // bid%8 = n%8 -> same-n blocks share an XCD
    const int lb   = blockIdx.y;         // L-tile of 256 rows

    const float* up_n = up + (size_t)n * D_DIM;

    // ---- phase 0: X tile (256 rows) -> LDS overlay, build both Xf sets ----
    half8 Xf0[4], Xf1[4];
    {
        const int xr = tid >> 1;                   // row 0..255
        const int xh = tid & 1;
        const float* xsrc = x + (size_t)(lb * 256 + xr) * ND + n * D_DIM;
        #pragma unroll
        for (int j = 0; j < 8; ++j) {
            const int f4i = xh * 8 + j;
            *(float4*)&Xs[xr][4 * f4i] = *(const float4*)(xsrc + 4 * f4i);
        }
        __syncthreads();
        const int rl0 = tw * 64 + l31;
        const int rl1 = rl0 + 32;
        #pragma unroll
        for (int kk = 0; kk < 4; ++kk) {
            float4 f1 = *(const float4*)&Xs[rl0][16 * kk + 8 * h];
            float4 f2 = *(const float4*)&Xs[rl0][16 * kk + 8 * h + 4];
            Xf0[kk] = mk_frag(pkh2(f1.x, f1.y), pkh2(f1.z, f1.w),
                              pkh2(f2.x, f2.y), pkh2(f2.z, f2.w));
            float4 f3 = *(const float4*)&Xs[rl1][16 * kk + 8 * h];
            float4 f4v = *(const float4*)&Xs[rl1][16 * kk + 8 * h + 4];
            Xf1[kk] = mk_frag(pkh2(f3.x, f3.y), pkh2(f3.z, f3.w),
                              pkh2(f4v.x, f4v.y), pkh2(f4v.z, f4v.w));
        }
        __syncthreads();   // Xs reads done before pack overwrites the overlay
    }

    floatx16 F00, F01, F10, F11;   // [lh][d-half] accumulators, full-O sweep
    #pragma unroll
    for (int i = 0; i < 16; ++i) { F00[i] = 0.0f; F01[i] = 0.0f;
                                   F10[i] = 0.0f; F11[i] = 0.0f; }

    for (int hb = 0; hb < 2; ++hb) {
        // ---- pack this half's 8 tiles into the LDS image (2 chunks/wave/tile) ----
        for (int tt = 0; tt < HALF_TILES; ++tt)
            pack_chunks(up_n, hb * HALF_TILES + tt, wid, lane,
                        simg + (size_t)tt * TILE_BYTES);
        __syncthreads();   // image resident (drains vm + lgkm)

        // ---- compute 8 tiles: even/odd register prefetch, zero barriers ----
        half8 AkE[4], G2E[4], AkO[4], G2O[4];
        load_frags(simg, team, lane, AkE, G2E);
        for (int t2 = 0; t2 < HALF_TILES; t2 += 2) {
            load_frags(simg + (size_t)(t2 + 1) * TILE_BYTES, team, lane, AkO, G2O);
            compute_tile(AkE, G2E, Xf0, Xf1, h, F00, F01, F10, F11);
            if (t2 + 2 < HALF_TILES)
                load_frags(simg + (size_t)(t2 + 2) * TILE_BYTES, team, lane, AkE, G2E);
            compute_tile(AkO, G2O, Xf0, Xf1, h, F00, F01, F10, F11);
        }
        __syncthreads();   // all waves done reading before repack / epilogue overlay
    }

    // ---- epilogue: team combine via LDS overlay, then direct store ----
    if (team == 1) {
        #pragma unroll
        for (int lh = 0; lh < 2; ++lh) {
            const int row = tw * 64 + lh * 32 + l31;
            const floatx16& A = lh ? F10 : F00;
            const floatx16& Bq = lh ? F11 : F01;
            #pragma unroll
            for (int q = 0; q < 4; ++q) {
                float4 a; a.x = A[4*q]; a.y = A[4*q+1]; a.z = A[4*q+2]; a.w = A[4*q+3];
                *(float4*)&Xs[row][8*q + 4*h] = a;            // d 0..31
                float4 b2; b2.x = Bq[4*q]; b2.y = Bq[4*q+1]; b2.z = Bq[4*q+2]; b2.w = Bq[4*q+3];
                *(float4*)&Xs[row][32 + 8*q + 4*h] = b2;      // d 32..63
            }
        }
    }
    __syncthreads();
    if (team == 0) {
        #pragma unroll
        for (int lh = 0; lh < 2; ++lh) {
            const int row = tw * 64 + lh * 32 + l31;
            const floatx16& A = lh ? F10 : F00;
            const floatx16& Bq = lh ? F11 : F01;
            float* op = out + (size_t)(lb * 256 + row) * ND + n * D_DIM;
            #pragma unroll
            for (int q = 0; q < 4; ++q) {
                float4 t0 = *(const float4*)&Xs[row][8*q + 4*h];
                float4 a; a.x = A[4*q]   + t0.x; a.y = A[4*q+1] + t0.y;
                          a.z = A[4*q+2] + t0.z; a.w = A[4*q+3] + t0.w;
                *(float4*)(op + 8*q + 4*h) = a;               // d 0..31
                float4 t1 = *(const float4*)&Xs[row][32 + 8*q + 4*h];
                float4 b2; b2.x = Bq[4*q]   + t1.x; b2.y = Bq[4*q+1] + t1.y;
                           b2.z = Bq[4*q+2] + t1.z; b2.w = Bq[4*q+3] + t1.w;
                *(float4*)(op + 32 + 8*q + 4*h) = b2;         // d 32..63
            }
        }
    }
}

extern "C" void kernel_launch(void* const* d_in, const int* in_sizes, int n_in,
                              void* d_out, int out_size, void* d_ws, size_t ws_size,
                              hipStream_t stream)
{
    const float* x  = (const float*)d_in[0];
    const float* up = (const float*)d_in[1];
    float* out      = (float*)d_out;
    dim3 grid(N_DIM, L_DIM / 256);   // 256 blocks = 1/CU; bid%8 = n%8 (XCD affinity)
    corr_lds<<<grid, dim3(512), 0, stream>>>(x, up, out);
}